// Round 2
// 103.114 us; speedup vs baseline: 1.0455x; 1.0455x over previous
//
#include <hip/hip_runtime.h>

// Multiprototypes: per-row squared distances to the 3 centers of the row's
// label, min-distance mean (loss1) and entropy-masked min-distance mean (loss2).
//
// B=262144, C=1000, K=3, D=64 (f32). HBM-bound: ~65 MB read -> ~10.8 us floor
// for mp_main (centers are 768 KB -> L2-resident).
//
// Mapping (v2): 4 lanes per row (each lane owns 16 elements = 4 float4),
// 16 rows/wave, 4 waves/block -> 64 rows per block-iteration, 2 iterations.
//   - shuffle butterfly is 2 stages (was 4), 6 swizzles per 16 rows (was 12 per 4 rows)
//   - 16 independent loads in flight per lane hides the labels->centers gather chain
// Per-block partial sums -> d_ws; 1-block finalize kernel writes out[0..1].

#define TH   0.95f
#define EPSF 1e-12f
#define NBLK 2048
#define BLK  256

__device__ __forceinline__ float dist16(const float4 xv0, const float4 xv1,
                                        const float4 xv2, const float4 xv3,
                                        const float4* __restrict__ cb) {
    // cb points at this lane's quarter (sub) of the 64-float center row;
    // quarters are strided 4 float4s apart.
    const float4 c0 = cb[0];
    const float4 c1 = cb[4];
    const float4 c2 = cb[8];
    const float4 c3 = cb[12];
    float d = xv0.x - c0.x; float s = d * d;
    d = xv0.y - c0.y; s = fmaf(d, d, s);
    d = xv0.z - c0.z; s = fmaf(d, d, s);
    d = xv0.w - c0.w; s = fmaf(d, d, s);
    d = xv1.x - c1.x; s = fmaf(d, d, s);
    d = xv1.y - c1.y; s = fmaf(d, d, s);
    d = xv1.z - c1.z; s = fmaf(d, d, s);
    d = xv1.w - c1.w; s = fmaf(d, d, s);
    d = xv2.x - c2.x; s = fmaf(d, d, s);
    d = xv2.y - c2.y; s = fmaf(d, d, s);
    d = xv2.z - c2.z; s = fmaf(d, d, s);
    d = xv2.w - c2.w; s = fmaf(d, d, s);
    d = xv3.x - c3.x; s = fmaf(d, d, s);
    d = xv3.y - c3.y; s = fmaf(d, d, s);
    d = xv3.z - c3.z; s = fmaf(d, d, s);
    d = xv3.w - c3.w; s = fmaf(d, d, s);
    return s;
}

__global__ __launch_bounds__(BLK, 4) void mp_main(
    const float* __restrict__ x,        // [B, 64]
    const int*   __restrict__ labels,   // [B]
    const float* __restrict__ centers,  // [1000, 3, 64]
    float*       __restrict__ partials, // [3 * NBLK]
    int B)
{
    const int tid  = threadIdx.x;
    const int lane = tid & 63;
    const int wave = tid >> 6;       // 0..3
    const int sub  = lane & 3;       // quarter of the row (16 floats each)
    const int r    = lane >> 2;      // row-within-wave 0..15

    const float4* __restrict__ x4 = (const float4*)x;
    const float4* __restrict__ c4 = (const float4*)centers;

    const int rows_per_block = B / NBLK;      // 128
    const int iters = rows_per_block >> 6;    // 2 (64 rows per block-iter)
    const int rbase = blockIdx.x * rows_per_block + wave * 16 + r;

    float s1 = 0.f, s2 = 0.f, sc = 0.f;

    for (int t = 0; t < iters; ++t) {
        const int row = rbase + (t << 6);

        // x: per instruction the wave covers 16 rows x 64 B = 16 full lines;
        // the 4 loads together cover 4 KB contiguous.
        const float4* xr = x4 + row * 16 + sub;
        const float4 xv0 = xr[0];
        const float4 xv1 = xr[4];
        const float4 xv2 = xr[8];
        const float4 xv3 = xr[12];

        const int lab = labels[row];             // 4 lanes same addr -> broadcast
        const float4* cb = c4 + lab * 48 + sub;  // lab*(K=3)*(16 float4/row)

        // 12 independent L2 loads in flight; one gather latency amortized.
        float a0 = dist16(xv0, xv1, xv2, xv3, cb);
        float a1 = dist16(xv0, xv1, xv2, xv3, cb + 16);
        float a2 = dist16(xv0, xv1, xv2, xv3, cb + 32);

        // 4-lane butterfly: every lane of the quad ends with full row sums
        a0 += __shfl_xor(a0, 1); a1 += __shfl_xor(a1, 1); a2 += __shfl_xor(a2, 1);
        a0 += __shfl_xor(a0, 2); a1 += __shfl_xor(a1, 2); a2 += __shfl_xor(a2, 2);

        const float mn  = fminf(a0, fminf(a1, a2));
        const float mx  = fmaxf(a0, fmaxf(a1, a2));
        const float mid = a0 + a1 + a2 - mn - mx;   // second smallest

        const float d0 = mn + EPSF, d1 = mid + EPSF;
        const float p  = d0 / (d0 + d1);            // p <= 0.5, strictly > 0
        const float q  = 1.f - p;
        const float ent = -(p * __log2f(p) + q * __log2f(q));
        const float msk = (ent <= TH) ? 1.f : 0.f;

        const float w = (sub == 0) ? 1.f : 0.f;     // count each row once
        s1 += w * mn;
        s2 += w * msk * mn;
        sc += w * msk;
    }

    // full-wave (64) butterfly reduce
    #pragma unroll
    for (int m = 1; m <= 32; m <<= 1) {
        s1 += __shfl_xor(s1, m);
        s2 += __shfl_xor(s2, m);
        sc += __shfl_xor(sc, m);
    }

    __shared__ float red[3][4];
    if (lane == 0) { red[0][wave] = s1; red[1][wave] = s2; red[2][wave] = sc; }
    __syncthreads();
    if (tid == 0) {
        partials[blockIdx.x]              = red[0][0] + red[0][1] + red[0][2] + red[0][3];
        partials[NBLK + blockIdx.x]       = red[1][0] + red[1][1] + red[1][2] + red[1][3];
        partials[2 * NBLK + blockIdx.x]   = red[2][0] + red[2][1] + red[2][2] + red[2][3];
    }
}

__global__ __launch_bounds__(BLK) void mp_final(
    const float* __restrict__ partials, float* __restrict__ out, float invB)
{
    const int tid  = threadIdx.x;
    const int lane = tid & 63;
    const int wave = tid >> 6;

    float s1 = 0.f, s2 = 0.f, sc = 0.f;
    for (int i = tid; i < NBLK; i += BLK) {
        s1 += partials[i];
        s2 += partials[NBLK + i];
        sc += partials[2 * NBLK + i];
    }
    #pragma unroll
    for (int m = 1; m <= 32; m <<= 1) {
        s1 += __shfl_xor(s1, m);
        s2 += __shfl_xor(s2, m);
        sc += __shfl_xor(sc, m);
    }
    __shared__ float red[3][4];
    if (lane == 0) { red[0][wave] = s1; red[1][wave] = s2; red[2][wave] = sc; }
    __syncthreads();
    if (tid == 0) {
        float t1 = red[0][0] + red[0][1] + red[0][2] + red[0][3];
        float t2 = red[1][0] + red[1][1] + red[1][2] + red[1][3];
        float t3 = red[2][0] + red[2][1] + red[2][2] + red[2][3];
        out[0] = t1 * invB;    // loss1 = mean(min_pos)
        out[1] = t2 / t3;      // loss2 = masked mean
    }
}

extern "C" void kernel_launch(void* const* d_in, const int* in_sizes, int n_in,
                              void* d_out, int out_size, void* d_ws, size_t ws_size,
                              hipStream_t stream) {
    const float* x       = (const float*)d_in[0];
    const int*   labels  = (const int*)d_in[1];
    const float* centers = (const float*)d_in[2];
    float* out      = (float*)d_out;
    float* partials = (float*)d_ws;   // 3*NBLK floats = 24 KB
    const int B = in_sizes[1];        // 262144

    mp_main<<<NBLK, BLK, 0, stream>>>(x, labels, centers, partials, B);
    mp_final<<<1, BLK, 0, stream>>>(partials, out, 1.0f / (float)B);
}

// Round 3
// 100.819 us; speedup vs baseline: 1.0693x; 1.0228x over previous
//
#include <hip/hip_runtime.h>

// Multiprototypes: per-row squared distances to the 3 centers of the row's
// label, min-distance mean (loss1) and entropy-masked min-distance mean (loss2).
//
// B=262144, C=1000, K=3, D=64 (f32). mp_main floor: ~74 MB @ 6.4 TB/s ~= 11.6 us
// (67 MB x + 1 MB labels + <=6 MB cold centers; centers are L2-resident after).
// Timed region also contains 2x 256MiB harness poison-fills (~82.5 us) we can't touch.
//
// Mapping (v3): 4 lanes per row (each lane owns 16 elements = 4 float4),
// 16 rows/wave, 4 waves/block -> 64 rows per block, NBLK=4096 blocks, ONE
// iteration per block: exactly one labels->centers dependent-gather chain per
// wave, hidden by ~16 resident waves/CU. Deterministic 2-kernel reduction
// (no float atomics -> absmax stays exact).

#define TH   0.95f
#define EPSF 1e-12f
#define NBLK 4096
#define BLK  256
#define BLKF 1024

__device__ __forceinline__ float dist16(const float4 xv0, const float4 xv1,
                                        const float4 xv2, const float4 xv3,
                                        const float4* __restrict__ cb) {
    // cb points at this lane's quarter (sub) of the 64-float center row;
    // quarters are strided 4 float4s apart.
    const float4 c0 = cb[0];
    const float4 c1 = cb[4];
    const float4 c2 = cb[8];
    const float4 c3 = cb[12];
    float d = xv0.x - c0.x; float s = d * d;
    d = xv0.y - c0.y; s = fmaf(d, d, s);
    d = xv0.z - c0.z; s = fmaf(d, d, s);
    d = xv0.w - c0.w; s = fmaf(d, d, s);
    d = xv1.x - c1.x; s = fmaf(d, d, s);
    d = xv1.y - c1.y; s = fmaf(d, d, s);
    d = xv1.z - c1.z; s = fmaf(d, d, s);
    d = xv1.w - c1.w; s = fmaf(d, d, s);
    d = xv2.x - c2.x; s = fmaf(d, d, s);
    d = xv2.y - c2.y; s = fmaf(d, d, s);
    d = xv2.z - c2.z; s = fmaf(d, d, s);
    d = xv2.w - c2.w; s = fmaf(d, d, s);
    d = xv3.x - c3.x; s = fmaf(d, d, s);
    d = xv3.y - c3.y; s = fmaf(d, d, s);
    d = xv3.z - c3.z; s = fmaf(d, d, s);
    d = xv3.w - c3.w; s = fmaf(d, d, s);
    return s;
}

__global__ __launch_bounds__(BLK, 4) void mp_main(
    const float* __restrict__ x,        // [B, 64]
    const int*   __restrict__ labels,   // [B]
    const float* __restrict__ centers,  // [1000, 3, 64]
    float*       __restrict__ partials, // [3 * NBLK]
    int B)
{
    const int tid  = threadIdx.x;
    const int lane = tid & 63;
    const int wave = tid >> 6;       // 0..3
    const int sub  = lane & 3;       // quarter of the row (16 floats each)
    const int r    = lane >> 2;      // row-within-wave 0..15

    const float4* __restrict__ x4 = (const float4*)x;
    const float4* __restrict__ c4 = (const float4*)centers;

    const int rows_per_block = B / NBLK;      // 64
    const int iters = rows_per_block >> 6;    // 1
    const int rbase = blockIdx.x * rows_per_block + wave * 16 + r;

    float s1 = 0.f, s2 = 0.f, sc = 0.f;

    for (int t = 0; t < iters; ++t) {
        const int row = rbase + (t << 6);

        // label first: starts the dependent gather chain as early as possible
        const int lab = labels[row];             // 4 lanes same addr -> broadcast

        // x: per instruction the wave covers 16 rows; 4 loads = 4 KB contiguous
        const float4* xr = x4 + row * 16 + sub;
        const float4 xv0 = xr[0];
        const float4 xv1 = xr[4];
        const float4 xv2 = xr[8];
        const float4 xv3 = xr[12];

        const float4* cb = c4 + lab * 48 + sub;  // lab*(K=3)*(16 float4/row)

        // 12 independent L2 loads in flight; one gather latency per wave total.
        float a0 = dist16(xv0, xv1, xv2, xv3, cb);
        float a1 = dist16(xv0, xv1, xv2, xv3, cb + 16);
        float a2 = dist16(xv0, xv1, xv2, xv3, cb + 32);

        // 4-lane butterfly: every lane of the quad ends with full row sums
        a0 += __shfl_xor(a0, 1); a1 += __shfl_xor(a1, 1); a2 += __shfl_xor(a2, 1);
        a0 += __shfl_xor(a0, 2); a1 += __shfl_xor(a1, 2); a2 += __shfl_xor(a2, 2);

        const float mn  = fminf(a0, fminf(a1, a2));
        const float mx  = fmaxf(a0, fmaxf(a1, a2));
        const float mid = a0 + a1 + a2 - mn - mx;   // second smallest

        const float d0 = mn + EPSF, d1 = mid + EPSF;
        const float p  = d0 / (d0 + d1);            // p <= 0.5, strictly > 0
        const float q  = 1.f - p;
        const float ent = -(p * __log2f(p) + q * __log2f(q));
        const float msk = (ent <= TH) ? 1.f : 0.f;

        if (sub == 0) {                             // count each row once
            s1 += mn;
            s2 += msk * mn;
            sc += msk;
        }
    }

    // full-wave (64) butterfly reduce
    #pragma unroll
    for (int m = 1; m <= 32; m <<= 1) {
        s1 += __shfl_xor(s1, m);
        s2 += __shfl_xor(s2, m);
        sc += __shfl_xor(sc, m);
    }

    __shared__ float red[3][4];
    if (lane == 0) { red[0][wave] = s1; red[1][wave] = s2; red[2][wave] = sc; }
    __syncthreads();
    if (tid == 0) {
        partials[blockIdx.x]              = red[0][0] + red[0][1] + red[0][2] + red[0][3];
        partials[NBLK + blockIdx.x]       = red[1][0] + red[1][1] + red[1][2] + red[1][3];
        partials[2 * NBLK + blockIdx.x]   = red[2][0] + red[2][1] + red[2][2] + red[2][3];
    }
}

__global__ __launch_bounds__(BLKF) void mp_final(
    const float* __restrict__ partials, float* __restrict__ out, float invB)
{
    const int tid  = threadIdx.x;
    const int lane = tid & 63;
    const int wave = tid >> 6;       // 0..15

    // 3*NBLK floats = 3*1024 float4; exactly one float4 per thread per array.
    const float4* p4 = (const float4*)partials;
    const float4 v1 = p4[tid];                    // partials[0      .. NBLK)
    const float4 v2 = p4[(NBLK >> 2) + tid];      // partials[NBLK   .. 2NBLK)
    const float4 v3 = p4[(NBLK >> 1) + tid];      // partials[2NBLK  .. 3NBLK)

    float s1 = v1.x + v1.y + v1.z + v1.w;
    float s2 = v2.x + v2.y + v2.z + v2.w;
    float sc = v3.x + v3.y + v3.z + v3.w;

    #pragma unroll
    for (int m = 1; m <= 32; m <<= 1) {
        s1 += __shfl_xor(s1, m);
        s2 += __shfl_xor(s2, m);
        sc += __shfl_xor(sc, m);
    }

    __shared__ float red[3][16];
    if (lane == 0) { red[0][wave] = s1; red[1][wave] = s2; red[2][wave] = sc; }
    __syncthreads();
    if (tid == 0) {
        float t1 = 0.f, t2 = 0.f, t3 = 0.f;
        #pragma unroll
        for (int i = 0; i < 16; ++i) { t1 += red[0][i]; t2 += red[1][i]; t3 += red[2][i]; }
        out[0] = t1 * invB;    // loss1 = mean(min_pos)
        out[1] = t2 / t3;      // loss2 = masked mean
    }
}

extern "C" void kernel_launch(void* const* d_in, const int* in_sizes, int n_in,
                              void* d_out, int out_size, void* d_ws, size_t ws_size,
                              hipStream_t stream) {
    const float* x       = (const float*)d_in[0];
    const int*   labels  = (const int*)d_in[1];
    const float* centers = (const float*)d_in[2];
    float* out      = (float*)d_out;
    float* partials = (float*)d_ws;   // 3*NBLK floats = 48 KB
    const int B = in_sizes[1];        // 262144

    mp_main<<<NBLK, BLK, 0, stream>>>(x, labels, centers, partials, B);
    mp_final<<<1, BLKF, 0, stream>>>(partials, out, 1.0f / (float)B);
}